// Round 13
// baseline (1515.397 us; speedup 1.0000x reference)
//
#include <hip/hip_runtime.h>
#include <hip/hip_fp16.h>

#define NB   256
#define TT   1024
#define II   64
#define NT   512

typedef _Float16 f16;
typedef _Float16 f16x4 __attribute__((ext_vector_type(4)));
typedef _Float16 hf8 __attribute__((ext_vector_type(8)));
typedef float    ff4 __attribute__((ext_vector_type(4)));

__device__ __forceinline__ float rcp_fast(float x){
    float r; asm("v_rcp_f32 %0, %1" : "=v"(r) : "v"(x)); return r;
}
__device__ __forceinline__ float exp2_fast(float x){
    float r; asm("v_exp_f32 %0, %1" : "=v"(r) : "v"(x)); return r;
}
__device__ __forceinline__ float sigm(float x){
    return rcp_fast(1.0f + exp2_fast(x * -1.44269504f));
}
__device__ __forceinline__ float tanh_f(float x){
    return fmaf(-2.0f, rcp_fast(1.0f + exp2_fast(x * 2.88539008f)), 1.0f);
}

// MFMA via inline asm, A-operand pinned in AGPR (matrix pipe reads AGPR
// natively on gfx950 -> no v_accvgpr_read moves). Hazard handling:
//  - first MFMA of each chain takes bias as SrcC (bias regs stable since
//    prologue -> no VALU-write->MFMA-read window)
//  - MFMA_FENCE: data-dependent s_nop block (32 cyc) between last MFMA and
//    the VALU select tree (covers MFMA-write->VALU-read wait states)
__device__ __forceinline__ ff4 mfma_init(const hf8& a, const hf8& b, const ff4& c){
    ff4 d;
    asm("v_mfma_f32_16x16x32_f16 %0, %1, %2, %3" : "=&v"(d) : "a"(a), "v"(b), "v"(c));
    return d;
}
__device__ __forceinline__ void mfma_acc(ff4& acc, const hf8& a, const hf8& b){
    asm("v_mfma_f32_16x16x32_f16 %0, %1, %2, %0" : "+v"(acc) : "a"(a), "v"(b));
}
#define MFMA_FENCE(A0,A1,A2,A3,A4,A5) \
    asm volatile("s_nop 7\n\ts_nop 7\n\ts_nop 7\n\ts_nop 7" \
        : "+v"(A0), "+v"(A1), "+v"(A2), "+v"(A3), "+v"(A4), "+v"(A5))

// Structure = R10 (best: 945us). 8 waves x 6 tiles (16 gate-interleaved rows).
// Tiles 0-31: L1 (K=192 over [x;h1]); 32-47: L2. Waves 0-4 pure L1,
// wave 5 = 2 L1 + 4 L2, waves 6-7 pure L2. A[6][6] hf8 = 144 regs in AGPR.
// C/D: col=lane&15 (dup cols), row=kg*4+reg [m89, verified R5-R11] =>
// lane (kg,rho) holds gates i,f,g,o of unit 4*tau_i+kg in acc[i];
// lane rho<6 activates tile i=rho (static cndmask tree).
// x: xchunk[64][64] f16 ring, 32 steps staged per 32 steps.

__launch_bounds__(NT, 2)
__global__ void lstm_mfma(const float* __restrict__ x,
                          const float* __restrict__ Wih1, const float* __restrict__ Whh1,
                          const float* __restrict__ bih1, const float* __restrict__ bhh1,
                          const float* __restrict__ Wih2, const float* __restrict__ Whh2,
                          const float* __restrict__ bih2, const float* __restrict__ bhh2,
                          const float* __restrict__ W1,   const float* __restrict__ b1,
                          const float* __restrict__ W2,   const float* __restrict__ b2,
                          float* __restrict__ out)
{
    __shared__ __align__(16) f16 xchunk[64][II];   // 8 KB
    __shared__ __align__(16) f16 h1buf[2][128];
    __shared__ __align__(16) f16 h2buf[2][64];
    __shared__ float headbuf[32];

    const int j    = threadIdx.x;      // 0..511
    const int b    = blockIdx.x;
    const int wave = j >> 6;           // 0..7
    const int lane = j & 63;
    const int rho  = lane & 15;
    const int kg   = lane >> 4;        // 0..3

    // ---------- one-time: A fragments + biases ----------
    hf8 A[6][6];
    ff4 bias[6];
    #pragma unroll
    for (int i = 0; i < 6; ++i){
        const int  tau = 6*wave + i;
        const bool l2  = (tau >= 32);
        #pragma unroll
        for (int kt = 0; kt < 6; ++kt){
            const int k = 32*kt + kg*8;
            const float* src;
            if (!l2){
                const int R = (rho & 3)*128 + 4*tau + (rho >> 2);
                src = (k < 64) ? (Wih1 + R*64 + k) : (Whh1 + R*128 + (k - 64));
            } else {
                const int R = (rho & 3)*64 + 4*(tau - 32) + (rho >> 2);
                src = (k < 128) ? (Wih2 + R*128 + k) : (Whh2 + R*64 + (k - 128));
            }
            float4 v0 = *(const float4*)src;
            float4 v1 = *(const float4*)(src + 4);
            hf8 a;
            a[0]=(f16)v0.x; a[1]=(f16)v0.y; a[2]=(f16)v0.z; a[3]=(f16)v0.w;
            a[4]=(f16)v1.x; a[5]=(f16)v1.y; a[6]=(f16)v1.z; a[7]=(f16)v1.w;
            A[i][kt] = a;
        }
        #pragma unroll
        for (int r = 0; r < 4; ++r){
            if (!l2){ const int R = r*128 + 4*tau + kg;        bias[i][r] = bih1[R] + bhh1[R]; }
            else    { const int R = r*64  + 4*(tau - 32) + kg; bias[i][r] = bih2[R] + bhh2[R]; }
        }
    }

    const int  myTau = 6*wave + rho;               // valid for rho<6
    const bool isl2  = (myTau >= 32);
    const int  myU   = isl2 ? 4*(myTau - 32) + kg : 4*myTau + kg;
    float c = 0.0f;

    const float* xb = x + (size_t)b * TT * II;

    // prologue: stage steps 0..31 (512 float4, one per thread); zero h
    {
        float4 v = ((const float4*)xb)[j];
        f16x4 w; w[0]=(f16)v.x; w[1]=(f16)v.y; w[2]=(f16)v.z; w[3]=(f16)v.w;
        *(f16x4*)&xchunk[j >> 4][(j & 15)*4] = w;
        if (j < 128) h1buf[0][j] = (f16)0.0f;
        if (j < 64)  h2buf[0][j] = (f16)0.0f;
    }
    __syncthreads();

    int cur = 0;
    for (int t = 0; t < TT; ++t){
        // chunk staging: once per 32 steps, issue loads early
        const bool stage = ((t & 31) == 0) && (t + 32 < TT);
        float4 sv;
        if (stage)
            sv = ((const float4*)(xb + (size_t)(t + 32)*II))[j];

        const f16* xr  = xchunk[t & 63];
        const f16* h1c = h1buf[cur];
        const f16* h2c = h2buf[cur];

        // ---- B fragments (per-wave window) ----
        hf8 bf[8];
        if (wave <= 5){
            bf[0] = *(const hf8*)(xr + kg*8);
            bf[1] = *(const hf8*)(xr + 32 + kg*8);
        }
        bf[2] = *(const hf8*)(h1c       + kg*8);
        bf[3] = *(const hf8*)(h1c + 32  + kg*8);
        bf[4] = *(const hf8*)(h1c + 64  + kg*8);
        bf[5] = *(const hf8*)(h1c + 96  + kg*8);
        if (wave >= 5){
            bf[6] = *(const hf8*)(h2c      + kg*8);
            bf[7] = *(const hf8*)(h2c + 32 + kg*8);
        }

        // ---- MFMA: 6 tiles x 6 kt (A from AGPR; bias folded as SrcC) ----
        ff4 acc[6];
        if (wave < 5){
            #pragma unroll
            for (int i = 0; i < 6; ++i) acc[i] = mfma_init(A[i][0], bf[0], bias[i]);
            #pragma unroll
            for (int kt = 1; kt < 6; ++kt){
                hf8 bb = bf[kt];
                #pragma unroll
                for (int i = 0; i < 6; ++i) mfma_acc(acc[i], A[i][kt], bb);
            }
        } else if (wave == 5){
            acc[0] = mfma_init(A[0][0], bf[0], bias[0]);
            acc[1] = mfma_init(A[1][0], bf[0], bias[1]);
            #pragma unroll
            for (int i = 2; i < 6; ++i) acc[i] = mfma_init(A[i][0], bf[2], bias[i]);
            #pragma unroll
            for (int kt = 1; kt < 6; ++kt){
                hf8 b1f = bf[kt];
                mfma_acc(acc[0], A[0][kt], b1f);
                mfma_acc(acc[1], A[1][kt], b1f);
                hf8 b2f = bf[kt + 2];
                #pragma unroll
                for (int i = 2; i < 6; ++i) mfma_acc(acc[i], A[i][kt], b2f);
            }
        } else {
            #pragma unroll
            for (int i = 0; i < 6; ++i) acc[i] = mfma_init(A[i][0], bf[2], bias[i]);
            #pragma unroll
            for (int kt = 1; kt < 6; ++kt){
                hf8 bb = bf[kt + 2];
                #pragma unroll
                for (int i = 0; i < 6; ++i) mfma_acc(acc[i], A[i][kt], bb);
            }
        }
        MFMA_FENCE(acc[0], acc[1], acc[2], acc[3], acc[4], acc[5]);

        // ---- select own tile's quad (static cndmask tree, rho<6) ----
        ff4 m0 = (rho & 1) ? acc[1] : acc[0];
        ff4 m1 = (rho & 1) ? acc[3] : acc[2];
        ff4 m2 = (rho & 1) ? acc[5] : acc[4];
        ff4 n0 = (rho & 2) ? m1 : m0;
        ff4 qd = (rho & 4) ? m2 : n0;

        // ---- in-lane activation ----
        float hv;
        if (isl2 && t == 0){
            hv = 0.0f;                     // h2_{-1}=0, c2 untouched
        } else {
            float ig = sigm(qd[0]);
            float fg = sigm(qd[1]);
            float gg = tanh_f(qd[2]);
            float og = sigm(qd[3]);
            c  = fg*c + ig*gg;
            hv = og * tanh_f(c);
        }
        if (rho < 6){
            if (isl2) h2buf[cur ^ 1][myU] = (f16)hv;
            else      h1buf[cur ^ 1][myU] = (f16)hv;
        }

        // staging publish (vm-wait lands here, overlapped with step compute)
        if (stage){
            f16x4 w; w[0]=(f16)sv.x; w[1]=(f16)sv.y; w[2]=(f16)sv.z; w[3]=(f16)sv.w;
            *(f16x4*)&xchunk[((t + 32) & 63) + (j >> 4)][(j & 15)*4] = w;
        }
        __syncthreads();
        cur ^= 1;
    }
    // after loop: cur==0; h1buf[0]=h1_{TT-1}, h2buf[0]=h2_{TT-2}

    // ---- epilogue: L2 step TT-1 (waves 5-7) ----
    if (wave >= 5){
        const f16* h1c = h1buf[0];
        const f16* h2c = h2buf[0];
        hf8 ebf[6];
        ebf[0] = *(const hf8*)(h1c      + kg*8);
        ebf[1] = *(const hf8*)(h1c + 32 + kg*8);
        ebf[2] = *(const hf8*)(h1c + 64 + kg*8);
        ebf[3] = *(const hf8*)(h1c + 96 + kg*8);
        ebf[4] = *(const hf8*)(h2c      + kg*8);
        ebf[5] = *(const hf8*)(h2c + 32 + kg*8);

        ff4 acc[6];
        if (wave == 5){
            acc[0] = bias[0]; acc[1] = bias[1];
            #pragma unroll
            for (int i = 2; i < 6; ++i) acc[i] = mfma_init(A[i][0], ebf[0], bias[i]);
            #pragma unroll
            for (int kt = 1; kt < 6; ++kt){
                hf8 bb = ebf[kt];
                #pragma unroll
                for (int i = 2; i < 6; ++i) mfma_acc(acc[i], A[i][kt], bb);
            }
        } else {
            #pragma unroll
            for (int i = 0; i < 6; ++i) acc[i] = mfma_init(A[i][0], ebf[0], bias[i]);
            #pragma unroll
            for (int kt = 1; kt < 6; ++kt){
                hf8 bb = ebf[kt];
                #pragma unroll
                for (int i = 0; i < 6; ++i) mfma_acc(acc[i], A[i][kt], bb);
            }
        }
        MFMA_FENCE(acc[0], acc[1], acc[2], acc[3], acc[4], acc[5]);

        ff4 m0 = (rho & 1) ? acc[1] : acc[0];
        ff4 m1 = (rho & 1) ? acc[3] : acc[2];
        ff4 m2 = (rho & 1) ? acc[5] : acc[4];
        ff4 n0 = (rho & 2) ? m1 : m0;
        ff4 qd = (rho & 4) ? m2 : n0;

        if (rho < 6 && isl2){
            float ig = sigm(qd[0]);
            float fg = sigm(qd[1]);
            float gg = tanh_f(qd[2]);
            float og = sigm(qd[3]);
            c = fg*c + ig*gg;
            float hv = og * tanh_f(c);
            h2buf[1][myU] = (f16)hv;
        }
    }
    __syncthreads();

    // ---- MLP head (final h2 in h2buf[1]) ----
    if (j < 32){
        float a = b1[j];
        const float* w = W1 + j*64;
        #pragma unroll
        for (int k = 0; k < 64; ++k) a = fmaf(w[k], (float)h2buf[1][k], a);
        headbuf[j] = sigm(a);
    }
    __syncthreads();
    if (j == 0){
        float a = b2[0];
        #pragma unroll
        for (int k = 0; k < 32; ++k) a = fmaf(W2[k], headbuf[k], a);
        out[b] = sigm(a);
    }
}

extern "C" void kernel_launch(void* const* d_in, const int* in_sizes, int n_in,
                              void* d_out, int out_size, void* d_ws, size_t ws_size,
                              hipStream_t stream)
{
    (void)in_sizes; (void)n_in; (void)d_ws; (void)ws_size; (void)out_size;
    lstm_mfma<<<NB, NT, 0, stream>>>(
        (const float*)d_in[0],
        (const float*)d_in[1], (const float*)d_in[2],
        (const float*)d_in[3], (const float*)d_in[4],
        (const float*)d_in[5], (const float*)d_in[6],
        (const float*)d_in[7], (const float*)d_in[8],
        (const float*)d_in[9], (const float*)d_in[10],
        (const float*)d_in[11], (const float*)d_in[12],
        (float*)d_out);
}

// Round 14
// 849.803 us; speedup vs baseline: 1.7832x; 1.7832x over previous
//
#include <hip/hip_runtime.h>
#include <hip/hip_fp16.h>

#define NB   256
#define TT   1024
#define II   64
#define NT   512

typedef _Float16 f16;
typedef _Float16 f16x4 __attribute__((ext_vector_type(4)));
typedef _Float16 hf8 __attribute__((ext_vector_type(8)));
typedef float    ff4 __attribute__((ext_vector_type(4)));

__device__ __forceinline__ float rcp_fast(float x){
    float r; asm("v_rcp_f32 %0, %1" : "=v"(r) : "v"(x)); return r;
}
__device__ __forceinline__ float exp2_fast(float x){
    float r; asm("v_exp_f32 %0, %1" : "=v"(r) : "v"(x)); return r;
}
__device__ __forceinline__ float sigm(float x){
    return rcp_fast(1.0f + exp2_fast(x * -1.44269504f));
}
__device__ __forceinline__ float tanh_f(float x){
    return fmaf(-2.0f, rcp_fast(1.0f + exp2_fast(x * 2.88539008f)), 1.0f);
}
__device__ __forceinline__ hf8 cvt8(float4 a, float4 b){
    hf8 r;
    r[0]=(f16)a.x; r[1]=(f16)a.y; r[2]=(f16)a.z; r[3]=(f16)a.w;
    r[4]=(f16)b.x; r[5]=(f16)b.y; r[6]=(f16)b.z; r[7]=(f16)b.w;
    return r;
}
__device__ __forceinline__ hf8 ldw8(const float* src){
    float4 v0 = *(const float4*)src;
    float4 v1 = *(const float4*)(src + 4);
    return cvt8(v0, v1);
}

// Gate-interleaved tiles (verified R5-R13): gate-row R = (rho&3)*H + 4*tau
// + (rho>>2); C/D: col=lane&15, row=kg*4+reg => lane (kg,rho) holds gates
// i,f,g,o of unit 4*tau+kg. B-frag col=lane&15 (verified by R11 passing).
//
// Waves 0-3: L1, 8 tiles each, K = h1 only (4 kt, 32 MFMA/step).
// Waves 4-7: L2, 4 tiles each, K = [h1;h2] (6 kt, 24 MFMA/step).
// Each SIMD hosts one L1 + one L2 wave (tail stagger).
// x-path: Wih1*x + bias precomputed 16 steps at a time as a GEMM with
// timesteps as B-columns (cols = lane&15 = timestep). xg[2][16][520] f16
// double-buffered; GEMM burst at t%16==15 (all waves, 4 tiles x 2 kt);
// per-step L1 consumption = one f16x4 scatter ds_read + 4 adds after the
// select tree. 228 MFMA/CU/step vs R10's 288. No xchunk.

__launch_bounds__(NT, 2)
__global__ void lstm_mfma(const float* __restrict__ x,
                          const float* __restrict__ Wih1, const float* __restrict__ Whh1,
                          const float* __restrict__ bih1, const float* __restrict__ bhh1,
                          const float* __restrict__ Wih2, const float* __restrict__ Whh2,
                          const float* __restrict__ bih2, const float* __restrict__ bhh2,
                          const float* __restrict__ W1,   const float* __restrict__ b1,
                          const float* __restrict__ W2,   const float* __restrict__ b2,
                          float* __restrict__ out)
{
    __shared__ __align__(16) f16 xg[2][16][520];   // 33 KB, row pad 520
    __shared__ __align__(16) f16 h1buf[2][128];
    __shared__ __align__(16) f16 h2buf[2][64];
    __shared__ float headbuf[32];

    const int j    = threadIdx.x;      // 0..511
    const int b    = blockIdx.x;
    const int wave = j >> 6;           // 0..7
    const int lane = j & 63;
    const int rho  = lane & 15;
    const int kg   = lane >> 4;        // 0..3
    const bool l2w = (wave >= 4);
    const int  wv  = wave & 3;

    const float* xb = x + (size_t)b * TT * II;

    // chunk-0 x loads first (latency covered by weight loading below)
    float4 xl0, xl1, xl2, xl3;
    {
        const float* xp = xb + (size_t)rho * II + kg*8;
        xl0 = *(const float4*)xp;       xl1 = *(const float4*)(xp + 4);
        xl2 = *(const float4*)(xp + 32);xl3 = *(const float4*)(xp + 36);
    }

    // ---------- weights ----------
    hf8 A[32];                          // L1: A[i*4+kt] i<8 | L2: A[i*6+kt] i<4
    ff4 bias2[4];
    if (!l2w){
        #pragma unroll
        for (int i = 0; i < 8; ++i){
            const int tau = 8*wv + i;
            const int R   = (rho & 3)*128 + 4*tau + (rho >> 2);
            #pragma unroll
            for (int kt = 0; kt < 4; ++kt)
                A[i*4 + kt] = ldw8(Whh1 + R*128 + 32*kt + kg*8);
        }
    } else {
        #pragma unroll
        for (int i = 0; i < 4; ++i){
            const int tau2 = 4*wv + i;
            const int R    = (rho & 3)*64 + 4*tau2 + (rho >> 2);
            #pragma unroll
            for (int kt = 0; kt < 6; ++kt)
                A[i*6 + kt] = ldw8((kt < 4) ? (Wih2 + R*128 + 32*kt + kg*8)
                                            : (Whh2 + R*64  + 32*(kt-4) + kg*8));
            #pragma unroll
            for (int r = 0; r < 4; ++r){
                const int Rb = r*64 + 4*tau2 + kg;
                bias2[i][r] = bih2[Rb] + bhh2[Rb];
            }
        }
    }
    // GEMM weights: 4 tiles per wave (32 total), K=64 (2 kkt)
    hf8 AX[8];
    ff4 biasX[4];
    #pragma unroll
    for (int i = 0; i < 4; ++i){
        const int tx = 4*wave + i;
        const int Rx = (rho & 3)*128 + 4*tx + (rho >> 2);
        AX[i*2 + 0] = ldw8(Wih1 + Rx*64 + kg*8);
        AX[i*2 + 1] = ldw8(Wih1 + Rx*64 + 32 + kg*8);
        #pragma unroll
        for (int r = 0; r < 4; ++r){
            const int Rb = r*128 + 4*tx + kg;
            biasX[i][r] = bih1[Rb] + bhh1[Rb];
        }
    }

    if (j < 128) h1buf[0][j] = (f16)0.0f;
    if (j < 64)  h2buf[0][j] = (f16)0.0f;

    // ---------- prologue GEMM: xg chunk 0 (steps 0..15) ----------
    {
        hf8 xh0 = cvt8(xl0, xl1);
        hf8 xh1 = cvt8(xl2, xl3);
        #pragma unroll
        for (int i = 0; i < 4; ++i){
            ff4 g = __builtin_amdgcn_mfma_f32_16x16x32_f16(AX[i*2+0], xh0, biasX[i], 0, 0, 0);
            g     = __builtin_amdgcn_mfma_f32_16x16x32_f16(AX[i*2+1], xh1, g,        0, 0, 0);
            const int uX = 4*(4*wave + i) + kg;
            f16x4 w; w[0]=(f16)g[0]; w[1]=(f16)g[1]; w[2]=(f16)g[2]; w[3]=(f16)g[3];
            *(f16x4*)&xg[0][rho][uX*4] = w;
        }
    }
    __syncthreads();

    const ff4 zz = {0.0f, 0.0f, 0.0f, 0.0f};
    float c = 0.0f;
    int cur = 0;
    for (int t = 0; t < TT; ++t){
        const int trow = t & 15;
        const int cb   = (t >> 4) & 1;
        const bool stage = (trow == 15) && (t + 1 < TT);

        // issue next chunk's x loads (consumed ~1000+cyc later this step)
        if (stage){
            const float* xp = xb + (size_t)(t + 1 + rho) * II + kg*8;
            xl0 = *(const float4*)xp;       xl1 = *(const float4*)(xp + 4);
            xl2 = *(const float4*)(xp + 32);xl3 = *(const float4*)(xp + 36);
        }

        const f16* h1c = h1buf[cur];
        hf8 bf0 = *(const hf8*)(h1c      + kg*8);
        hf8 bf1 = *(const hf8*)(h1c + 32 + kg*8);
        hf8 bf2 = *(const hf8*)(h1c + 64 + kg*8);
        hf8 bf3 = *(const hf8*)(h1c + 96 + kg*8);

        ff4 qd;
        float xadd0 = 0.f, xadd1 = 0.f, xadd2 = 0.f, xadd3 = 0.f;
        if (!l2w){
            // per-lane xg scatter read (unit clamped for rho>=8 dup lanes)
            const int myUm = (4*(8*wv + rho) + kg) & 127;
            f16x4 xv = *(const f16x4*)&xg[cb][trow][myUm*4];
            xadd0 = (float)xv[0]; xadd1 = (float)xv[1];
            xadd2 = (float)xv[2]; xadd3 = (float)xv[3];

            ff4 acc[8];
            #pragma unroll
            for (int i = 0; i < 8; ++i)
                acc[i] = __builtin_amdgcn_mfma_f32_16x16x32_f16(A[i*4+0], bf0, zz, 0, 0, 0);
            #pragma unroll
            for (int i = 0; i < 8; ++i)
                acc[i] = __builtin_amdgcn_mfma_f32_16x16x32_f16(A[i*4+1], bf1, acc[i], 0, 0, 0);
            #pragma unroll
            for (int i = 0; i < 8; ++i)
                acc[i] = __builtin_amdgcn_mfma_f32_16x16x32_f16(A[i*4+2], bf2, acc[i], 0, 0, 0);
            #pragma unroll
            for (int i = 0; i < 8; ++i)
                acc[i] = __builtin_amdgcn_mfma_f32_16x16x32_f16(A[i*4+3], bf3, acc[i], 0, 0, 0);

            ff4 s0 = (rho & 1) ? acc[1] : acc[0];
            ff4 s1 = (rho & 1) ? acc[3] : acc[2];
            ff4 s2 = (rho & 1) ? acc[5] : acc[4];
            ff4 s3 = (rho & 1) ? acc[7] : acc[6];
            ff4 u0 = (rho & 2) ? s1 : s0;
            ff4 u1 = (rho & 2) ? s3 : s2;
            qd     = (rho & 4) ? u1 : u0;
        } else {
            const f16* h2c = h2buf[cur];
            hf8 bf4 = *(const hf8*)(h2c      + kg*8);
            hf8 bf5 = *(const hf8*)(h2c + 32 + kg*8);
            ff4 acc[4];
            #pragma unroll
            for (int i = 0; i < 4; ++i)
                acc[i] = __builtin_amdgcn_mfma_f32_16x16x32_f16(A[i*6+0], bf0, bias2[i], 0, 0, 0);
            #pragma unroll
            for (int kt = 1; kt < 6; ++kt){
                hf8 bb = (kt==1)?bf1:(kt==2)?bf2:(kt==3)?bf3:(kt==4)?bf4:bf5;
                #pragma unroll
                for (int i = 0; i < 4; ++i)
                    acc[i] = __builtin_amdgcn_mfma_f32_16x16x32_f16(A[i*6+kt], bb, acc[i], 0, 0, 0);
            }
            ff4 s0 = (rho & 1) ? acc[1] : acc[0];
            ff4 s1 = (rho & 1) ? acc[3] : acc[2];
            qd     = (rho & 2) ? s1 : s0;
        }

        // ---- GEMM burst for next chunk (all waves, t%16==15) ----
        if (stage){
            hf8 xh0 = cvt8(xl0, xl1);
            hf8 xh1 = cvt8(xl2, xl3);
            #pragma unroll
            for (int i = 0; i < 4; ++i){
                ff4 g = __builtin_amdgcn_mfma_f32_16x16x32_f16(AX[i*2+0], xh0, biasX[i], 0, 0, 0);
                g     = __builtin_amdgcn_mfma_f32_16x16x32_f16(AX[i*2+1], xh1, g,        0, 0, 0);
                const int uX = 4*(4*wave + i) + kg;
                f16x4 w; w[0]=(f16)g[0]; w[1]=(f16)g[1]; w[2]=(f16)g[2]; w[3]=(f16)g[3];
                *(f16x4*)&xg[cb ^ 1][rho][uX*4] = w;
            }
        }

        // ---- in-lane activation ----
        if (!l2w){
            float ig = sigm(qd[0] + xadd0);
            float fg = sigm(qd[1] + xadd1);
            float gg = tanh_f(qd[2] + xadd2);
            float og = sigm(qd[3] + xadd3);
            c = fg*c + ig*gg;
            float hv = og * tanh_f(c);
            if (rho < 8) h1buf[cur ^ 1][4*(8*wv + rho) + kg] = (f16)hv;
        } else {
            float hv;
            if (t > 0){
                float ig = sigm(qd[0]);
                float fg = sigm(qd[1]);
                float gg = tanh_f(qd[2]);
                float og = sigm(qd[3]);
                c = fg*c + ig*gg;
                hv = og * tanh_f(c);
            } else {
                hv = 0.0f;                 // h2_{-1}=0, c2 untouched
            }
            if (rho < 4) h2buf[cur ^ 1][4*(4*wv + rho) + kg] = (f16)hv;
        }
        __syncthreads();
        cur ^= 1;
    }
    // after loop: cur==0; h1buf[0]=h1_{TT-1}, h2buf[0]=h2_{TT-2}

    // ---- epilogue: L2 step TT-1 (waves 4-7) ----
    if (l2w){
        const f16* h1c = h1buf[0];
        const f16* h2c = h2buf[0];
        hf8 bf0 = *(const hf8*)(h1c      + kg*8);
        hf8 bf1 = *(const hf8*)(h1c + 32 + kg*8);
        hf8 bf2 = *(const hf8*)(h1c + 64 + kg*8);
        hf8 bf3 = *(const hf8*)(h1c + 96 + kg*8);
        hf8 bf4 = *(const hf8*)(h2c      + kg*8);
        hf8 bf5 = *(const hf8*)(h2c + 32 + kg*8);
        ff4 acc[4];
        #pragma unroll
        for (int i = 0; i < 4; ++i)
            acc[i] = __builtin_amdgcn_mfma_f32_16x16x32_f16(A[i*6+0], bf0, bias2[i], 0, 0, 0);
        #pragma unroll
        for (int kt = 1; kt < 6; ++kt){
            hf8 bb = (kt==1)?bf1:(kt==2)?bf2:(kt==3)?bf3:(kt==4)?bf4:bf5;
            #pragma unroll
            for (int i = 0; i < 4; ++i)
                acc[i] = __builtin_amdgcn_mfma_f32_16x16x32_f16(A[i*6+kt], bb, acc[i], 0, 0, 0);
        }
        ff4 s0 = (rho & 1) ? acc[1] : acc[0];
        ff4 s1 = (rho & 1) ? acc[3] : acc[2];
        ff4 qd = (rho & 2) ? s1 : s0;
        float ig = sigm(qd[0]);
        float fg = sigm(qd[1]);
        float gg = tanh_f(qd[2]);
        float og = sigm(qd[3]);
        c = fg*c + ig*gg;
        float hv = og * tanh_f(c);
        if (rho < 4) h2buf[1][4*(4*wv + rho) + kg] = (f16)hv;
    }
    __syncthreads();

    // ---- MLP head (final h2 in h2buf[1]) ----
    if (j < 32){
        float a = b1[j];
        const float* w = W1 + j*64;
        #pragma unroll
        for (int k = 0; k < 64; ++k) a = fmaf(w[k], (float)h2buf[1][k], a);
        headbuf[j] = sigm(a);
    }
    __syncthreads();
    if (j == 0){
        float a = b2[0];
        #pragma unroll
        for (int k = 0; k < 32; ++k) a = fmaf(W2[k], headbuf[k], a);
        out[b] = sigm(a);
    }
}

extern "C" void kernel_launch(void* const* d_in, const int* in_sizes, int n_in,
                              void* d_out, int out_size, void* d_ws, size_t ws_size,
                              hipStream_t stream)
{
    (void)in_sizes; (void)n_in; (void)d_ws; (void)ws_size; (void)out_size;
    lstm_mfma<<<NB, NT, 0, stream>>>(
        (const float*)d_in[0],
        (const float*)d_in[1], (const float*)d_in[2],
        (const float*)d_in[3], (const float*)d_in[4],
        (const float*)d_in[5], (const float*)d_in[6],
        (const float*)d_in[7], (const float*)d_in[8],
        (const float*)d_in[9], (const float*)d_in[10],
        (const float*)d_in[11], (const float*)d_in[12],
        (float*)d_out);
}

// Round 15
// 817.601 us; speedup vs baseline: 1.8535x; 1.0394x over previous
//
#include <hip/hip_runtime.h>
#include <hip/hip_fp16.h>

#define NB   256
#define TT   1024
#define II   64
#define NT   512

typedef _Float16 f16;
typedef _Float16 f16x4 __attribute__((ext_vector_type(4)));
typedef _Float16 hf8 __attribute__((ext_vector_type(8)));
typedef float    ff4 __attribute__((ext_vector_type(4)));

__device__ __forceinline__ float rcp_fast(float x){
    float r; asm("v_rcp_f32 %0, %1" : "=v"(r) : "v"(x)); return r;
}
__device__ __forceinline__ float exp2_fast(float x){
    float r; asm("v_exp_f32 %0, %1" : "=v"(r) : "v"(x)); return r;
}
__device__ __forceinline__ float sigm(float x){
    return rcp_fast(1.0f + exp2_fast(x * -1.44269504f));
}
__device__ __forceinline__ float tanh_f(float x){
    return fmaf(-2.0f, rcp_fast(1.0f + exp2_fast(x * 2.88539008f)), 1.0f);
}
__device__ __forceinline__ hf8 cvt8(float4 a, float4 b){
    hf8 r;
    r[0]=(f16)a.x; r[1]=(f16)a.y; r[2]=(f16)a.z; r[3]=(f16)a.w;
    r[4]=(f16)b.x; r[5]=(f16)b.y; r[6]=(f16)b.z; r[7]=(f16)b.w;
    return r;
}
__device__ __forceinline__ hf8 ldw8(const float* src){
    float4 v0 = *(const float4*)src;
    float4 v1 = *(const float4*)(src + 4);
    return cvt8(v0, v1);
}

// Structure = R14 (best: 849us) + phase-stagger:
//  - L2 waves' MFMA cluster wrapped in s_setprio(1) -> L2 finishes MFMA early,
//    its VALU tail overlaps L1's remaining MFMA issue (T5: role-split waves).
//  - xg scatter read hoisted before the MFMA cluster (latency hidden).
//  - xg clamp rho&7 (true broadcast for dup lanes -> bank conflicts gone).
//  - bias2 slimmed to 4 scalars/lane, added after the select tree.
// Tiles: gate-interleaved (verified R5-R14). Waves 0-3: L1, 8 tiles x 4 h-kt.
// Waves 4-7: L2, 4 tiles x 6 kt. GEMM x-path: xg[2][16][520] f16 dbuf,
// burst every 16 steps on all waves (4 tiles x 2 kt).

__launch_bounds__(NT, 2)
__global__ void lstm_mfma(const float* __restrict__ x,
                          const float* __restrict__ Wih1, const float* __restrict__ Whh1,
                          const float* __restrict__ bih1, const float* __restrict__ bhh1,
                          const float* __restrict__ Wih2, const float* __restrict__ Whh2,
                          const float* __restrict__ bih2, const float* __restrict__ bhh2,
                          const float* __restrict__ W1,   const float* __restrict__ b1,
                          const float* __restrict__ W2,   const float* __restrict__ b2,
                          float* __restrict__ out)
{
    __shared__ __align__(16) f16 xg[2][16][520];   // 33 KB, row pad 520
    __shared__ __align__(16) f16 h1buf[2][128];
    __shared__ __align__(16) f16 h2buf[2][64];
    __shared__ float headbuf[32];

    const int j    = threadIdx.x;      // 0..511
    const int b    = blockIdx.x;
    const int wave = j >> 6;           // 0..7
    const int lane = j & 63;
    const int rho  = lane & 15;
    const int kg   = lane >> 4;        // 0..3
    const bool l2w = (wave >= 4);
    const int  wv  = wave & 3;

    const float* xb = x + (size_t)b * TT * II;

    // chunk-0 x loads first (latency covered by weight loading below)
    float4 xl0, xl1, xl2, xl3;
    {
        const float* xp = xb + (size_t)rho * II + kg*8;
        xl0 = *(const float4*)xp;       xl1 = *(const float4*)(xp + 4);
        xl2 = *(const float4*)(xp + 32);xl3 = *(const float4*)(xp + 36);
    }

    // ---------- weights ----------
    hf8 A[32];                          // L1: A[i*4+kt] i<8 | L2: A[i*6+kt] i<4
    float b2l0 = 0.f, b2l1 = 0.f, b2l2 = 0.f, b2l3 = 0.f;   // L2 bias (own unit)
    if (!l2w){
        #pragma unroll
        for (int i = 0; i < 8; ++i){
            const int tau = 8*wv + i;
            const int R   = (rho & 3)*128 + 4*tau + (rho >> 2);
            #pragma unroll
            for (int kt = 0; kt < 4; ++kt)
                A[i*4 + kt] = ldw8(Whh1 + R*128 + 32*kt + kg*8);
        }
    } else {
        #pragma unroll
        for (int i = 0; i < 4; ++i){
            const int tau2 = 4*wv + i;
            const int R    = (rho & 3)*64 + 4*tau2 + (rho >> 2);
            #pragma unroll
            for (int kt = 0; kt < 6; ++kt)
                A[i*6 + kt] = ldw8((kt < 4) ? (Wih2 + R*128 + 32*kt + kg*8)
                                            : (Whh2 + R*64  + 32*(kt-4) + kg*8));
        }
        const int u2 = 4*(4*wv + (rho & 3)) + kg;   // own unit (clamped dup)
        b2l0 = bih2[u2]       + bhh2[u2];
        b2l1 = bih2[64 + u2]  + bhh2[64 + u2];
        b2l2 = bih2[128 + u2] + bhh2[128 + u2];
        b2l3 = bih2[192 + u2] + bhh2[192 + u2];
    }
    // GEMM weights: 4 tiles per wave (32 total), K=64 (2 kkt)
    hf8 AX[8];
    ff4 biasX[4];
    #pragma unroll
    for (int i = 0; i < 4; ++i){
        const int tx = 4*wave + i;
        const int Rx = (rho & 3)*128 + 4*tx + (rho >> 2);
        AX[i*2 + 0] = ldw8(Wih1 + Rx*64 + kg*8);
        AX[i*2 + 1] = ldw8(Wih1 + Rx*64 + 32 + kg*8);
        #pragma unroll
        for (int r = 0; r < 4; ++r){
            const int Rb = r*128 + 4*tx + kg;
            biasX[i][r] = bih1[Rb] + bhh1[Rb];
        }
    }

    if (j < 128) h1buf[0][j] = (f16)0.0f;
    if (j < 64)  h2buf[0][j] = (f16)0.0f;

    // ---------- prologue GEMM: xg chunk 0 (steps 0..15) ----------
    {
        hf8 xh0 = cvt8(xl0, xl1);
        hf8 xh1 = cvt8(xl2, xl3);
        #pragma unroll
        for (int i = 0; i < 4; ++i){
            ff4 g = __builtin_amdgcn_mfma_f32_16x16x32_f16(AX[i*2+0], xh0, biasX[i], 0, 0, 0);
            g     = __builtin_amdgcn_mfma_f32_16x16x32_f16(AX[i*2+1], xh1, g,        0, 0, 0);
            const int uX = 4*(4*wave + i) + kg;
            f16x4 w; w[0]=(f16)g[0]; w[1]=(f16)g[1]; w[2]=(f16)g[2]; w[3]=(f16)g[3];
            *(f16x4*)&xg[0][rho][uX*4] = w;
        }
    }
    __syncthreads();

    const ff4 zz = {0.0f, 0.0f, 0.0f, 0.0f};
    float c = 0.0f;
    int cur = 0;
    for (int t = 0; t < TT; ++t){
        const int trow = t & 15;
        const int cb   = (t >> 4) & 1;
        const bool stage = (trow == 15) && (t + 1 < TT);

        // issue next chunk's x loads (consumed later this step, L3-resident)
        if (stage){
            const float* xp = xb + (size_t)(t + 1 + rho) * II + kg*8;
            xl0 = *(const float4*)xp;       xl1 = *(const float4*)(xp + 4);
            xl2 = *(const float4*)(xp + 32);xl3 = *(const float4*)(xp + 36);
        }

        // xg scatter read hoisted (L1 only; rho&7 clamp -> broadcast dup)
        f16x4 xv = {};
        if (!l2w){
            const int myUm = 4*(8*wv + (rho & 7)) + kg;
            xv = *(const f16x4*)&xg[cb][trow][myUm*4];
        }

        const f16* h1c = h1buf[cur];
        hf8 bf0 = *(const hf8*)(h1c      + kg*8);
        hf8 bf1 = *(const hf8*)(h1c + 32 + kg*8);
        hf8 bf2 = *(const hf8*)(h1c + 64 + kg*8);
        hf8 bf3 = *(const hf8*)(h1c + 96 + kg*8);

        ff4 qd;
        if (!l2w){
            ff4 acc[8];
            #pragma unroll
            for (int i = 0; i < 8; ++i)
                acc[i] = __builtin_amdgcn_mfma_f32_16x16x32_f16(A[i*4+0], bf0, zz, 0, 0, 0);
            #pragma unroll
            for (int i = 0; i < 8; ++i)
                acc[i] = __builtin_amdgcn_mfma_f32_16x16x32_f16(A[i*4+1], bf1, acc[i], 0, 0, 0);
            #pragma unroll
            for (int i = 0; i < 8; ++i)
                acc[i] = __builtin_amdgcn_mfma_f32_16x16x32_f16(A[i*4+2], bf2, acc[i], 0, 0, 0);
            #pragma unroll
            for (int i = 0; i < 8; ++i)
                acc[i] = __builtin_amdgcn_mfma_f32_16x16x32_f16(A[i*4+3], bf3, acc[i], 0, 0, 0);

            ff4 s0 = (rho & 1) ? acc[1] : acc[0];
            ff4 s1 = (rho & 1) ? acc[3] : acc[2];
            ff4 s2 = (rho & 1) ? acc[5] : acc[4];
            ff4 s3 = (rho & 1) ? acc[7] : acc[6];
            ff4 u0 = (rho & 2) ? s1 : s0;
            ff4 u1 = (rho & 2) ? s3 : s2;
            qd     = (rho & 4) ? u1 : u0;
        } else {
            const f16* h2c = h2buf[cur];
            hf8 bf4 = *(const hf8*)(h2c      + kg*8);
            hf8 bf5 = *(const hf8*)(h2c + 32 + kg*8);
            ff4 acc[4];
            __builtin_amdgcn_s_setprio(1);     // T5: L2 wins issue -> staggers
            #pragma unroll
            for (int i = 0; i < 4; ++i)
                acc[i] = __builtin_amdgcn_mfma_f32_16x16x32_f16(A[i*6+0], bf0, zz, 0, 0, 0);
            #pragma unroll
            for (int kt = 1; kt < 6; ++kt){
                hf8 bb = (kt==1)?bf1:(kt==2)?bf2:(kt==3)?bf3:(kt==4)?bf4:bf5;
                #pragma unroll
                for (int i = 0; i < 4; ++i)
                    acc[i] = __builtin_amdgcn_mfma_f32_16x16x32_f16(A[i*6+kt], bb, acc[i], 0, 0, 0);
            }
            __builtin_amdgcn_s_setprio(0);
            ff4 s0 = (rho & 1) ? acc[1] : acc[0];
            ff4 s1 = (rho & 1) ? acc[3] : acc[2];
            qd     = (rho & 2) ? s1 : s0;
            qd[0] += b2l0; qd[1] += b2l1; qd[2] += b2l2; qd[3] += b2l3;
        }

        // ---- GEMM burst for next chunk (all waves, t%16==15) ----
        if (stage){
            hf8 xh0 = cvt8(xl0, xl1);
            hf8 xh1 = cvt8(xl2, xl3);
            #pragma unroll
            for (int i = 0; i < 4; ++i){
                ff4 g = __builtin_amdgcn_mfma_f32_16x16x32_f16(AX[i*2+0], xh0, biasX[i], 0, 0, 0);
                g     = __builtin_amdgcn_mfma_f32_16x16x32_f16(AX[i*2+1], xh1, g,        0, 0, 0);
                const int uX = 4*(4*wave + i) + kg;
                f16x4 w; w[0]=(f16)g[0]; w[1]=(f16)g[1]; w[2]=(f16)g[2]; w[3]=(f16)g[3];
                *(f16x4*)&xg[cb ^ 1][rho][uX*4] = w;
            }
        }

        // ---- in-lane activation ----
        if (!l2w){
            float ig = sigm(qd[0] + (float)xv[0]);
            float fg = sigm(qd[1] + (float)xv[1]);
            float gg = tanh_f(qd[2] + (float)xv[2]);
            float og = sigm(qd[3] + (float)xv[3]);
            c = fg*c + ig*gg;
            float hv = og * tanh_f(c);
            if (rho < 8) h1buf[cur ^ 1][4*(8*wv + rho) + kg] = (f16)hv;
        } else {
            float hv;
            if (t > 0){
                float ig = sigm(qd[0]);
                float fg = sigm(qd[1]);
                float gg = tanh_f(qd[2]);
                float og = sigm(qd[3]);
                c = fg*c + ig*gg;
                hv = og * tanh_f(c);
            } else {
                hv = 0.0f;                 // h2_{-1}=0, c2 untouched
            }
            if (rho < 4) h2buf[cur ^ 1][4*(4*wv + rho) + kg] = (f16)hv;
        }
        __syncthreads();
        cur ^= 1;
    }
    // after loop: cur==0; h1buf[0]=h1_{TT-1}, h2buf[0]=h2_{TT-2}

    // ---- epilogue: L2 step TT-1 (waves 4-7) ----
    if (l2w){
        const f16* h1c = h1buf[0];
        const f16* h2c = h2buf[0];
        hf8 bf0 = *(const hf8*)(h1c      + kg*8);
        hf8 bf1 = *(const hf8*)(h1c + 32 + kg*8);
        hf8 bf2 = *(const hf8*)(h1c + 64 + kg*8);
        hf8 bf3 = *(const hf8*)(h1c + 96 + kg*8);
        hf8 bf4 = *(const hf8*)(h2c      + kg*8);
        hf8 bf5 = *(const hf8*)(h2c + 32 + kg*8);
        ff4 acc[4];
        const ff4 zz2 = {0.0f, 0.0f, 0.0f, 0.0f};
        #pragma unroll
        for (int i = 0; i < 4; ++i)
            acc[i] = __builtin_amdgcn_mfma_f32_16x16x32_f16(A[i*6+0], bf0, zz2, 0, 0, 0);
        #pragma unroll
        for (int kt = 1; kt < 6; ++kt){
            hf8 bb = (kt==1)?bf1:(kt==2)?bf2:(kt==3)?bf3:(kt==4)?bf4:bf5;
            #pragma unroll
            for (int i = 0; i < 4; ++i)
                acc[i] = __builtin_amdgcn_mfma_f32_16x16x32_f16(A[i*6+kt], bb, acc[i], 0, 0, 0);
        }
        ff4 s0 = (rho & 1) ? acc[1] : acc[0];
        ff4 s1 = (rho & 1) ? acc[3] : acc[2];
        ff4 qd = (rho & 2) ? s1 : s0;
        float ig = sigm(qd[0] + b2l0);
        float fg = sigm(qd[1] + b2l1);
        float gg = tanh_f(qd[2] + b2l2);
        float og = sigm(qd[3] + b2l3);
        c = fg*c + ig*gg;
        float hv = og * tanh_f(c);
        if (rho < 4) h2buf[1][4*(4*wv + rho) + kg] = (f16)hv;
    }
    __syncthreads();

    // ---- MLP head (final h2 in h2buf[1]) ----
    if (j < 32){
        float a = b1[j];
        const float* w = W1 + j*64;
        #pragma unroll
        for (int k = 0; k < 64; ++k) a = fmaf(w[k], (float)h2buf[1][k], a);
        headbuf[j] = sigm(a);
    }
    __syncthreads();
    if (j == 0){
        float a = b2[0];
        #pragma unroll
        for (int k = 0; k < 32; ++k) a = fmaf(W2[k], headbuf[k], a);
        out[b] = sigm(a);
    }
}

extern "C" void kernel_launch(void* const* d_in, const int* in_sizes, int n_in,
                              void* d_out, int out_size, void* d_ws, size_t ws_size,
                              hipStream_t stream)
{
    (void)in_sizes; (void)n_in; (void)d_ws; (void)ws_size; (void)out_size;
    lstm_mfma<<<NB, NT, 0, stream>>>(
        (const float*)d_in[0],
        (const float*)d_in[1], (const float*)d_in[2],
        (const float*)d_in[3], (const float*)d_in[4],
        (const float*)d_in[5], (const float*)d_in[6],
        (const float*)d_in[7], (const float*)d_in[8],
        (const float*)d_in[9], (const float*)d_in[10],
        (const float*)d_in[11], (const float*)d_in[12],
        (float*)d_out);
}